// Round 23
// baseline (434.979 us; speedup 1.0000x reference)
//
#include <hip/hip_runtime.h>
#include <math.h>

// Problem: B=128, P=128, D=128, N=4096, fp32 in/out.
// probs = softmax(10*tanh((A@K)/sqrt(128)) + mask) over n.
//
// R23: 32 rows/wave (B-fragment reuse x2). Diagnosis: R13-R22 all ~210us
// regardless of conflicts/scheduling/occupancy -> LDS B-read volume is the
// floor (32B/output). Doubling rows/wave halves it. 256-thr blocks escape
// the VGPR cap law (131072/(256*3) = 170) so A-frags x2 fit with slack.
//  K1: e = exp(10*tanh(score/sqrt(128)) + mask) -> O; row partials -> ws.
//      (max-free softmax: |10tanh| <= 10 -> e <= 2.3e4, sum <= 9e7)
//  K2: O *= 1/rowsum (32 partials per row).
constexpr int BB = 128;
constexpr int PP = 128;
constexpr int DD = 128;
constexpr int NN = 4096;
constexpr float kC = 10.0f;
constexpr float k2InvSqrtD = 0.1767766952966369f;   // 2/sqrt(128)

constexpr int NTHR = 256;            // 4 waves; each wave owns 32 rows
constexpr int TEL = 272;             // f16 elems per 16x16 tile incl pad (544 B)

typedef float f32x4 __attribute__((ext_vector_type(4)));
typedef _Float16 f16x4 __attribute__((ext_vector_type(4)));
typedef _Float16 f16x8 __attribute__((ext_vector_type(8)));

__device__ __forceinline__ void st_nt_f4(float* p, float4 s) {
    f32x4 v = {s.x, s.y, s.z, s.w};
    __builtin_nontemporal_store(v, (f32x4*)p);
}

// Hardware transpose read (HW-verified R15): lane l (addr = tile + 8l)
// receives tile elems (l&15) + 16j + 64*(l>>4) of a row-major [16d][16n]
// tile: d_local = j + 4*(l>>4), n_local = l&15.
__device__ __forceinline__ f16x4 tr_read(unsigned addr) {
    f16x4 r;
    asm volatile("ds_read_b64_tr_b16 %0, %1" : "=v"(r) : "v"(addr));
    return r;
}

// z = 10*tanh(s/sqrt(128)) + m, via tanh(x) = 1 - 2/(e^{2x}+1)
__device__ __forceinline__ float clip1(float s, float m) {
    const float e2 = __expf(s * k2InvSqrtD);
    const float r = __builtin_amdgcn_rcpf(e2 + 1.0f);
    return fmaf(-2.0f * kC, r, kC) + m;
}

// ===================== Kernel 1: staged GEMM + clip + exp =====================
// Grid: 4096 = 128 b x 32 n-tiles(128 cols). 256 thr = 4 waves; wave w owns
// rows w*32..+31 (TWO 16-row groups sharing each B-fragment), 128 cols as
// 2 halves x 4 nts.
// fp16x3: score = hh + hl + lh; k-packing d = kb*32 + 4g + (j&3) + 16*(j>>2)
// identical on A (regs) and B (tr reads) -> k-permutation errors cancel.
// C/D layout (HW-verified): col = lane&15, row = 4*(lane>>4) + reg.
// LDS: ONE half-buffer (128d x 64n) as 8x4 grid of 16x16 hi/lo tiles;
// tr reads conflict-free (R15-R22: SQ_LDS_BANK_CONFLICT = 0).
__global__ __launch_bounds__(NTHR, 3)    // cap 170 VGPR; design ~120 live
void score_kernel(const float* __restrict__ A,   // [B][P][D]
                  const float* __restrict__ K,   // [B][D][N]
                  const float* __restrict__ M,   // [B][P][N]
                  float* __restrict__ O,         // [B][P][N] <- exp(z)
                  float* __restrict__ ws) {      // [B*P][32] partial row sums
    __shared__ _Float16 Khi[32 * TEL];           // 17.4 KB
    __shared__ _Float16 Klo[32 * TEL];           // 17.4 KB

    const int l = blockIdx.x;
    const int b = l >> 5;
    const int ntb = l & 31;
    const int n_base = ntb * 128;

    const int tid = (int)threadIdx.x;
    const int lane = tid & 63;
    const int wid = tid >> 6;              // 0..3; wave rows = wid*32..+31
    const int col = lane & 15;             // A row-in-frag / B col / C col
    const int g = lane >> 4;               // k-group / C row group
    const int kbase = 4 * g;

    // ---- A fragments (regs, whole kernel): 2 row-groups x 128 d per wave ----
    f16x8 ah[2][4], al[2][4];
    #pragma unroll
    for (int rg = 0; rg < 2; ++rg) {
        const float* Arow = A + (size_t)(b * PP + wid * 32 + rg * 16 + col) * DD;
        #pragma unroll
        for (int kb = 0; kb < 4; ++kb) {
            #pragma unroll
            for (int j = 0; j < 8; ++j) {
                const int d = kb * 32 + kbase + (j & 3) + 16 * (j >> 2);
                const float x = Arow[d];
                const _Float16 h = (_Float16)x;
                ah[rg][kb][j] = h;
                al[rg][kb][j] = (_Float16)(x - (float)h);
            }
        }
    }

    const size_t mrow0A = (size_t)(b * PP + wid * 32 + kbase) * NN + n_base + col;
    const size_t mrow0B = mrow0A + (size_t)16 * NN;   // second row-group
    const unsigned khi0 = (unsigned)(uintptr_t)&Khi[0] + (unsigned)lane * 8u;
    const unsigned klo0 = (unsigned)(uintptr_t)&Klo[0] + (unsigned)lane * 8u;

    const float* Kg = K + (size_t)b * DD * NN + n_base;
    const int nl4 = (tid & 15) * 4;        // 4 consecutive n within the half
    const int d0 = tid >> 4;               // base d (0..15); d = d0 + 16*i
    const int el0 = (nl4 >> 4) * TEL + d0 * 16 + (nl4 & 12);

    float rsum[8] = {0.f, 0.f, 0.f, 0.f, 0.f, 0.f, 0.f, 0.f};

    // rolling 2-deep mask prefetch (16 regs)
    float mv[8], mvn[8];
    #pragma unroll
    for (int j = 0; j < 4; ++j) {
        mv[j] = M[mrow0A + (size_t)j * NN];
        mv[4 + j] = M[mrow0B + (size_t)j * NN];
        mvn[j] = M[mrow0A + (size_t)j * NN + 16];
        mvn[4 + j] = M[mrow0B + (size_t)j * NN + 16];
    }

    #pragma unroll
    for (int half = 0; half < 2; ++half) {
        if (half) __syncthreads();         // all reads of prev half done

        // ---- stage this half's K (128 d x 64 n) hi/lo, b64 writes ----
        #pragma unroll
        for (int i = 0; i < 8; ++i) {      // d-tile = i
            const float4 v = *(const float4*)(Kg + (size_t)(d0 + 16 * i) * NN
                                              + half * 64 + nl4);
            const float xs[4] = {v.x, v.y, v.z, v.w};
            f16x4 h, lo;
            #pragma unroll
            for (int e = 0; e < 4; ++e) {
                const _Float16 hh = (_Float16)xs[e];
                h[e] = hh;
                lo[e] = (_Float16)(xs[e] - (float)hh);
            }
            const int el = el0 + i * 4 * TEL;
            *(f16x4*)&Khi[el] = h;
            *(f16x4*)&Klo[el] = lo;
        }
        __syncthreads();

        // ---- 4 n-subtiles of this half ----
        #pragma unroll
        for (int nt2 = 0; nt2 < 4; ++nt2) {
            const int nt = half * 4 + nt2;

            f32x4 accA = {0.f, 0.f, 0.f, 0.f};
            f32x4 accB = {0.f, 0.f, 0.f, 0.f};
            // per-kb: 4 tr reads -> wait -> 6 MFMA (B-frags shared by 2 rgs)
            #pragma unroll
            for (int kb = 0; kb < 4; ++kb) {
                const unsigned t0 = (unsigned)(((2 * kb) * 4 + nt2) * 544);
                const f16x4 bh0 = tr_read(khi0 + t0);
                const f16x4 bh1 = tr_read(khi0 + t0 + 4u * 544u);
                const f16x4 bl0 = tr_read(klo0 + t0);
                const f16x4 bl1 = tr_read(klo0 + t0 + 4u * 544u);
                asm volatile("s_waitcnt lgkmcnt(0)" ::: "memory");
                __builtin_amdgcn_sched_barrier(0);     // rule #18
                const f16x8 bh = __builtin_shufflevector(bh0, bh1, 0, 1, 2, 3, 4, 5, 6, 7);
                const f16x8 bl = __builtin_shufflevector(bl0, bl1, 0, 1, 2, 3, 4, 5, 6, 7);
                accA = __builtin_amdgcn_mfma_f32_16x16x32_f16(ah[0][kb], bh, accA, 0, 0, 0);
                accA = __builtin_amdgcn_mfma_f32_16x16x32_f16(ah[0][kb], bl, accA, 0, 0, 0);
                accA = __builtin_amdgcn_mfma_f32_16x16x32_f16(al[0][kb], bh, accA, 0, 0, 0);
                accB = __builtin_amdgcn_mfma_f32_16x16x32_f16(ah[1][kb], bh, accB, 0, 0, 0);
                accB = __builtin_amdgcn_mfma_f32_16x16x32_f16(ah[1][kb], bl, accB, 0, 0, 0);
                accB = __builtin_amdgcn_mfma_f32_16x16x32_f16(al[1][kb], bh, accB, 0, 0, 0);
            }

            // epilogue: e = exp(clip + mask); store; partials (both row-groups)
            #pragma unroll
            for (int j = 0; j < 4; ++j) {
                const size_t offA = mrow0A + (size_t)j * NN + nt * 16;
                const float eA = __expf(clip1(accA[j], mv[j]));
                O[offA] = eA;
                rsum[j] += eA;
                const size_t offB = mrow0B + (size_t)j * NN + nt * 16;
                const float eB = __expf(clip1(accB[j], mv[4 + j]));
                O[offB] = eB;
                rsum[4 + j] += eB;
            }

            // rotate mask pipeline (distance 2)
            #pragma unroll
            for (int j = 0; j < 8; ++j) mv[j] = mvn[j];
            if (nt + 2 < 8) {
                #pragma unroll
                for (int j = 0; j < 4; ++j) {
                    mvn[j] = M[mrow0A + (size_t)j * NN + (nt + 2) * 16];
                    mvn[4 + j] = M[mrow0B + (size_t)j * NN + (nt + 2) * 16];
                }
            }
        }
    }

    // ---- reduce row partials across the 16 cols of each group -> ws ----
    #pragma unroll
    for (int q = 0; q < 8; ++q) {
        float s = rsum[q];
        s += __shfl_xor(s, 1);
        s += __shfl_xor(s, 2);
        s += __shfl_xor(s, 4);
        s += __shfl_xor(s, 8);
        rsum[q] = s;
    }
    if (col == 0) {
        #pragma unroll
        for (int rg = 0; rg < 2; ++rg)
            #pragma unroll
            for (int j = 0; j < 4; ++j)
                ws[(size_t)(b * PP + wid * 32 + rg * 16 + kbase + j) * 32 + ntb]
                    = rsum[rg * 4 + j];
    }
}

// ========================= Kernel 2: scale by 1/rowsum ========================
// Pure streaming: 2048 blocks x 256 thr; 32 threads/row, 32 f4/thread.
__global__ __launch_bounds__(256, 4)
void scale_kernel(float* __restrict__ O, const float* __restrict__ ws) {
    const int gtid = blockIdx.x * 256 + (int)threadIdx.x;
    const int row = gtid >> 5;
    const int seg = gtid & 31;

    const float* w = ws + (size_t)row * 32;
    float s = 0.f;
    #pragma unroll
    for (int i = 0; i < 8; ++i) {
        const float4 v = *(const float4*)(w + i * 4);
        s += (v.x + v.y) + (v.z + v.w);
    }
    const float inv = __builtin_amdgcn_rcpf(s);

    float4* R = (float4*)(O + (size_t)row * NN);
    #pragma unroll 8
    for (int i = 0; i < 32; ++i) {
        const int idx = i * 32 + seg;      // lanes consecutive -> coalesced
        float4 v = R[idx];
        v.x *= inv; v.y *= inv; v.z *= inv; v.w *= inv;
        st_nt_f4((float*)&R[idx], v);
    }
}

extern "C" void kernel_launch(void* const* d_in, const int* in_sizes, int n_in,
                              void* d_out, int out_size, void* d_ws, size_t ws_size,
                              hipStream_t stream) {
    const float* A = (const float*)d_in[0];   // mh_attn_out [128][128][128]
    const float* K = (const float*)d_in[1];   // single_head_key [128][128][4096]
    const float* M = (const float*)d_in[2];   // mask [128][128][4096]
    float* O = (float*)d_out;                 // probs [128][128][4096]
    float* ws = (float*)d_ws;                 // 16384 rows x 32 partials = 2 MB

    score_kernel<<<dim3(BB * 32), dim3(NTHR), 0, stream>>>(A, K, M, O, ws);
    scale_kernel<<<dim3(2048), dim3(256), 0, stream>>>(O, ws);
}

// Round 24
// 274.879 us; speedup vs baseline: 1.5824x; 1.5824x over previous
//
#include <hip/hip_runtime.h>
#include <math.h>

// Problem: B=128, P=128, D=128, N=4096, fp32 in/out.
// probs = softmax(10*tanh((A@K)/sqrt(128)) + mask) over n.
//
// R24: operand-SWAPPED MFMA (C holds score^T per-tile) -> each lane owns 4
// CONSECUTIVE n at fixed p, so the epilogue is one float4 M-load + one
// float4 O-store per nt (was 4+4 scalar). k-packing identical on both
// operands (permutation cancels); operand lane-conventions are symmetric
// (proven by R11-R23 passing); C/D map (HW-verified) reused with roles
// exchanged: row=4g+j -> n_local, col=lane&15 -> p.
//  K1: e = exp(10*tanh(score/sqrt(128)) + mask) -> O; row partials -> ws.
//      (max-free softmax: |10tanh| <= 10 -> e <= 2.3e4, sum <= 9e7)
//  K2: O *= 1/rowsum (32 partials per row).
constexpr int BB = 128;
constexpr int PP = 128;
constexpr int DD = 128;
constexpr int NN = 4096;
constexpr float kC = 10.0f;
constexpr float k2InvSqrtD = 0.1767766952966369f;   // 2/sqrt(128)

constexpr int NTHR = 512;
constexpr int TEL = 272;             // f16 elems per 16x16 tile incl pad (544 B)

typedef float f32x4 __attribute__((ext_vector_type(4)));
typedef _Float16 f16x4 __attribute__((ext_vector_type(4)));
typedef _Float16 f16x8 __attribute__((ext_vector_type(8)));

__device__ __forceinline__ void st_nt_f4(float* p, float4 s) {
    f32x4 v = {s.x, s.y, s.z, s.w};
    __builtin_nontemporal_store(v, (f32x4*)p);
}

// Hardware transpose read (HW-verified R15): lane l (addr = tile + 8l)
// receives tile elems (l&15) + 16j + 64*(l>>4) of a row-major [16d][16n]
// tile: d_local = j + 4*(l>>4), n_local = l&15.
__device__ __forceinline__ f16x4 tr_read(unsigned addr) {
    f16x4 r;
    asm volatile("ds_read_b64_tr_b16 %0, %1" : "=v"(r) : "v"(addr));
    return r;
}

// z = 10*tanh(s/sqrt(128)) + m, via tanh(x) = 1 - 2/(e^{2x}+1)
__device__ __forceinline__ float clip1(float s, float m) {
    const float e2 = __expf(s * k2InvSqrtD);
    const float r = __builtin_amdgcn_rcpf(e2 + 1.0f);
    return fmaf(-2.0f * kC, r, kC) + m;
}

// ===================== Kernel 1: staged GEMM + clip + exp =====================
// Grid: 4096 = 128 b x 32 n-tiles(128 cols). 512 thr = 8 waves; wave w owns
// rows w*16..+15, 128 cols as 2 halves x 4 nts.
// fp16x3: score = hh + hl + lh; k-packing d = kb*32 + 4g + (j&3) + 16*(j>>2)
// identical on BOTH operands -> k-permutation errors cancel.
// SWAPPED C/D: lane holds C[n_local=4g+j][p=lane&15], j=0..3 -> 4 consecutive n.
// LDS: ONE half-buffer (128d x 64n) as 8x4 grid of 16x16 hi/lo tiles;
// tr reads conflict-free (R15-R23: SQ_LDS_BANK_CONFLICT = 0).
__global__ __launch_bounds__(NTHR, 2)    // cap 128; design ~80 live
void score_kernel(const float* __restrict__ A,   // [B][P][D]
                  const float* __restrict__ K,   // [B][D][N]
                  const float* __restrict__ M,   // [B][P][N]
                  float* __restrict__ O,         // [B][P][N] <- exp(z)
                  float* __restrict__ ws) {      // [B*P][32] partial row sums
    __shared__ _Float16 Khi[32 * TEL];           // 17.4 KB
    __shared__ _Float16 Klo[32 * TEL];           // 17.4 KB

    const int l = blockIdx.x;
    const int b = l >> 5;
    const int ntb = l & 31;
    const int n_base = ntb * 128;

    const int tid = (int)threadIdx.x;
    const int lane = tid & 63;
    const int wid = tid >> 6;
    const int col = lane & 15;             // p row-in-tile (both operands' free idx)
    const int g = lane >> 4;               // k-group; also n-subgroup in C
    const int kbase = 4 * g;

    // ---- A fragments (regs, whole kernel): 16 rows x 128 d per wave ----
    const float* Arow = A + (size_t)(b * PP + wid * 16 + col) * DD;
    f16x8 ah[4], al[4];
    #pragma unroll
    for (int kb = 0; kb < 4; ++kb) {
        #pragma unroll
        for (int j = 0; j < 8; ++j) {
            const int d = kb * 32 + kbase + (j & 3) + 16 * (j >> 2);
            const float x = Arow[d];
            const _Float16 h = (_Float16)x;
            ah[kb][j] = h;
            al[kb][j] = (_Float16)(x - (float)h);
        }
    }

    // per-lane output row base: p = wid*16 + col, cols n_base + nt*16 + 4g + j
    const size_t prow0 = (size_t)(b * PP + wid * 16 + col) * NN + n_base + 4 * g;
    const unsigned khi0 = (unsigned)(uintptr_t)&Khi[0] + (unsigned)lane * 8u;
    const unsigned klo0 = (unsigned)(uintptr_t)&Klo[0] + (unsigned)lane * 8u;

    const float* Kg = K + (size_t)b * DD * NN + n_base;
    const int nl4 = (tid & 15) * 4;        // 4 consecutive n within the half
    const int d0 = tid >> 4;               // base d (0..31)
    const int el0 = ((d0 >> 4) * 4 + (nl4 >> 4)) * TEL + (d0 & 15) * 16 + (nl4 & 12);

    float rsum = 0.f;                      // ONE partial per lane (its p-row)

    // rolling 2-deep mask prefetch, float4 per lane
    float4 mv = *(const float4*)(M + prow0);
    float4 mvn = *(const float4*)(M + prow0 + 16);

    #pragma unroll
    for (int half = 0; half < 2; ++half) {
        if (half) __syncthreads();         // all reads of prev half done

        // ---- stage this half's K (128 d x 64 n) hi/lo, b64 writes ----
        #pragma unroll
        for (int i = 0; i < 4; ++i) {
            const float4 v = *(const float4*)(Kg + (size_t)(d0 + 32 * i) * NN
                                              + half * 64 + nl4);
            const float xs[4] = {v.x, v.y, v.z, v.w};
            f16x4 h, lo;
            #pragma unroll
            for (int e = 0; e < 4; ++e) {
                const _Float16 hh = (_Float16)xs[e];
                h[e] = hh;
                lo[e] = (_Float16)(xs[e] - (float)hh);
            }
            const int el = el0 + i * 8 * TEL;
            *(f16x4*)&Khi[el] = h;
            *(f16x4*)&Klo[el] = lo;
        }
        __syncthreads();

        // ---- 4 n-subtiles of this half ----
        #pragma unroll
        for (int nt2 = 0; nt2 < 4; ++nt2) {
            const int nt = half * 4 + nt2;

            f32x4 acc = {0.f, 0.f, 0.f, 0.f};
            // per-kb: 4 tr reads -> wait -> 3 MFMA (operands SWAPPED)
            #pragma unroll
            for (int kb = 0; kb < 4; ++kb) {
                const unsigned t0 = (unsigned)(((2 * kb) * 4 + nt2) * 544);
                const f16x4 bh0 = tr_read(khi0 + t0);
                const f16x4 bh1 = tr_read(khi0 + t0 + 4u * 544u);
                const f16x4 bl0 = tr_read(klo0 + t0);
                const f16x4 bl1 = tr_read(klo0 + t0 + 4u * 544u);
                asm volatile("s_waitcnt lgkmcnt(0)" ::: "memory");
                __builtin_amdgcn_sched_barrier(0);     // rule #18
                const f16x8 bh = __builtin_shufflevector(bh0, bh1, 0, 1, 2, 3, 4, 5, 6, 7);
                const f16x8 bl = __builtin_shufflevector(bl0, bl1, 0, 1, 2, 3, 4, 5, 6, 7);
                acc = __builtin_amdgcn_mfma_f32_16x16x32_f16(bh, ah[kb], acc, 0, 0, 0);
                acc = __builtin_amdgcn_mfma_f32_16x16x32_f16(bl, ah[kb], acc, 0, 0, 0);
                acc = __builtin_amdgcn_mfma_f32_16x16x32_f16(bh, al[kb], acc, 0, 0, 0);
            }

            // epilogue: e = exp(clip + mask); ONE f4 store; scalar partial
            {
                const size_t off = prow0 + (size_t)nt * 16;
                float4 e;
                e.x = __expf(clip1(acc[0], mv.x));
                e.y = __expf(clip1(acc[1], mv.y));
                e.z = __expf(clip1(acc[2], mv.z));
                e.w = __expf(clip1(acc[3], mv.w));
                *(float4*)(O + off) = e;   // cached: K2 re-reads via L2/L3
                rsum += (e.x + e.y) + (e.z + e.w);
            }

            // rotate mask pipeline (distance 2)
            mv = mvn;
            if (nt + 2 < 8)
                mvn = *(const float4*)(M + prow0 + (size_t)(nt + 2) * 16);
        }
    }

    // ---- reduce across the 4 g-groups of each p-row -> ws ----
    rsum += __shfl_xor(rsum, 16);
    rsum += __shfl_xor(rsum, 32);
    if (g == 0)
        ws[(size_t)(b * PP + wid * 16 + col) * 32 + ntb] = rsum;
}

// ========================= Kernel 2: scale by 1/rowsum ========================
// Pure streaming: 2048 blocks x 256 thr; 32 threads/row, 32 f4/thread.
__global__ __launch_bounds__(256, 4)
void scale_kernel(float* __restrict__ O, const float* __restrict__ ws) {
    const int gtid = blockIdx.x * 256 + (int)threadIdx.x;
    const int row = gtid >> 5;
    const int seg = gtid & 31;

    const float* w = ws + (size_t)row * 32;
    float s = 0.f;
    #pragma unroll
    for (int i = 0; i < 8; ++i) {
        const float4 v = *(const float4*)(w + i * 4);
        s += (v.x + v.y) + (v.z + v.w);
    }
    const float inv = __builtin_amdgcn_rcpf(s);

    float4* R = (float4*)(O + (size_t)row * NN);
    #pragma unroll 8
    for (int i = 0; i < 32; ++i) {
        const int idx = i * 32 + seg;      // lanes consecutive -> coalesced
        float4 v = R[idx];
        v.x *= inv; v.y *= inv; v.z *= inv; v.w *= inv;
        st_nt_f4((float*)&R[idx], v);
    }
}

extern "C" void kernel_launch(void* const* d_in, const int* in_sizes, int n_in,
                              void* d_out, int out_size, void* d_ws, size_t ws_size,
                              hipStream_t stream) {
    const float* A = (const float*)d_in[0];   // mh_attn_out [128][128][128]
    const float* K = (const float*)d_in[1];   // single_head_key [128][128][4096]
    const float* M = (const float*)d_in[2];   // mask [128][128][4096]
    float* O = (float*)d_out;                 // probs [128][128][4096]
    float* ws = (float*)d_ws;                 // 16384 rows x 32 partials = 2 MB

    score_kernel<<<dim3(BB * 32), dim3(NTHR), 0, stream>>>(A, K, M, O, ws);
    scale_kernel<<<dim3(2048), dim3(256), 0, stream>>>(O, ws);
}